// Round 1
// baseline (431.003 us; speedup 1.0000x reference)
//
#include <hip/hip_runtime.h>

// CrossHeadOnlineHadamardHook: y[b, h, d] = (1/sqrt(32)) * sum_k H32[h,k] x[b, k, d]
// H32 is the Sylvester Hadamard matrix -> use in-register FWHT (5 butterfly stages).
//
// Layout: x is (16384 tokens, 32 heads, 128 dims) fp32, contiguous.
// Each thread handles one token and 4 consecutive dims (one float4 column):
//   32 coalesced float4 loads (stride 128 floats), FWHT in registers, 32 stores.
// Memory-bound: 512 MiB total traffic, floor ~85 us at 6.3 TB/s.

#define HEADS 32
#define HDIM 128
#define ROW_F4 (HDIM / 4)          // 32 float4 per head row
#define TOKEN_F4 (HEADS * ROW_F4)  // 1024 float4 per token
#define BLOCK 256
#define DGROUPS ROW_F4             // 32 threads cover one token's 128 dims
#define TOK_PER_BLOCK (BLOCK / DGROUPS)  // 8 tokens per block

__global__ __launch_bounds__(BLOCK)
void hadamard_heads_kernel(const float4* __restrict__ x,
                           float4* __restrict__ y,
                           int ntokens) {
    const int tid   = blockIdx.x * BLOCK + threadIdx.x;
    const int token = tid / DGROUPS;     // which token
    const int dg    = tid % DGROUPS;     // which float4 column within the token
    if (token >= ntokens) return;

    const size_t base = (size_t)token * TOKEN_F4 + dg;
    const float4* xp = x + base;

    float4 v[HEADS];
#pragma unroll
    for (int k = 0; k < HEADS; ++k) {
        v[k] = xp[k * ROW_F4];
    }

    // 5-stage FWHT across heads (Sylvester / Hadamard natural ordering)
#pragma unroll
    for (int s = 1; s < HEADS; s <<= 1) {
#pragma unroll
        for (int k = 0; k < HEADS; ++k) {
            if ((k & s) == 0) {
                float4 a = v[k];
                float4 b = v[k + s];
                v[k]     = make_float4(a.x + b.x, a.y + b.y, a.z + b.z, a.w + b.w);
                v[k + s] = make_float4(a.x - b.x, a.y - b.y, a.z - b.z, a.w - b.w);
            }
        }
    }

    const float scale = 0.17677669529663687f;  // 1/sqrt(32)
    float4* yp = y + base;
#pragma unroll
    for (int k = 0; k < HEADS; ++k) {
        float4 a = v[k];
        yp[k * ROW_F4] = make_float4(a.x * scale, a.y * scale, a.z * scale, a.w * scale);
    }
}

extern "C" void kernel_launch(void* const* d_in, const int* in_sizes, int n_in,
                              void* d_out, int out_size, void* d_ws, size_t ws_size,
                              hipStream_t stream) {
    const float* x = (const float*)d_in[0];
    // d_in[1] (had_K) is the Sylvester Hadamard matrix by construction; FWHT replaces it.
    float* y = (float*)d_out;

    const int ntokens = in_sizes[0] / (HEADS * HDIM);  // 16384
    const int blocks = (ntokens + TOK_PER_BLOCK - 1) / TOK_PER_BLOCK;

    hadamard_heads_kernel<<<blocks, BLOCK, 0, stream>>>(
        (const float4*)x, (float4*)y, ntokens);
}

// Round 2
// 416.303 us; speedup vs baseline: 1.0353x; 1.0353x over previous
//
#include <hip/hip_runtime.h>

// CrossHeadOnlineHadamardHook: y[token, h, d] = (1/sqrt(32)) * sum_k H32[h,k] x[token, k, d]
// H32 = Sylvester Hadamard -> in-register FWHT. Stages of the FWHT commute
// (H32 = H2 tensor-power, one stage per head-index bit), so we do:
//   - 4 stages (s=1,2,4,8) in-thread over 16 locally-held heads
//   - final stage (s=16) via __shfl_xor across wave halves
//
// Mapping: one wave (64 lanes) = one token. lane = a*32 + dg:
//   a  = lane>>5 : which 16-head half (heads [a*16, a*16+16))
//   dg = lane&31 : which float4 column of the 128-dim head_dim
// Per load j: lanes 0..31 read a contiguous 512B segment, lanes 32..63 read
// another contiguous 512B segment -> fully coalesced dwordx4.
//
// 64 data VGPRs/thread (vs 128 before) -> higher occupancy; non-temporal
// loads/stores keep the 512 MiB stream out of L2.

typedef float f4 __attribute__((ext_vector_type(4)));

#define HEADS 32
#define ROW_F4 32            // float4 per head row (128 dims / 4)
#define TOKEN_F4 (HEADS * ROW_F4)  // 1024
#define BLOCK 256
#define TOK_PER_BLOCK (BLOCK / 64) // one wave per token -> 4

__global__ __launch_bounds__(BLOCK)
void hadamard_heads_kernel(const f4* __restrict__ x,
                           f4* __restrict__ y,
                           int ntokens) {
    const int tid   = blockIdx.x * BLOCK + threadIdx.x;
    const int token = tid >> 6;        // one wave per token
    const int lane  = tid & 63;
    const int a     = lane >> 5;       // head-half: 0 -> heads 0..15, 1 -> 16..31
    const int dg    = lane & 31;       // float4 column
    if (token >= ntokens) return;

    const size_t base = (size_t)token * TOKEN_F4 + (size_t)a * 16 * ROW_F4 + dg;
    const f4* xp = x + base;
    f4* yp = y + base;

    f4 v[16];
#pragma unroll
    for (int j = 0; j < 16; ++j) {
        v[j] = __builtin_nontemporal_load(&xp[j * ROW_F4]);
    }

    // 4 in-thread FWHT stages across the 16 locally-held heads
#pragma unroll
    for (int s = 1; s < 16; s <<= 1) {
#pragma unroll
        for (int j = 0; j < 16; ++j) {
            if ((j & s) == 0) {
                f4 p = v[j];
                f4 q = v[j + s];
                v[j]     = p + q;
                v[j + s] = p - q;
            }
        }
    }

    // Final stage (s=16): exchange with the other 32-lane half.
    // a=0 lanes hold v[k], a=1 lanes hold v[k+16]:
    //   new v[k]    = v[k] + v[k+16]   (a=0: mine + other)
    //   new v[k+16] = v[k] - v[k+16]   (a=1: other - mine)
    const float sgn = (a == 0) ? 1.0f : -1.0f;
#pragma unroll
    for (int j = 0; j < 16; ++j) {
        f4 o;
        o.x = __shfl_xor(v[j].x, 32);
        o.y = __shfl_xor(v[j].y, 32);
        o.z = __shfl_xor(v[j].z, 32);
        o.w = __shfl_xor(v[j].w, 32);
        v[j] = o + sgn * v[j];
    }

    const float scale = 0.17677669529663687f;  // 1/sqrt(32)
#pragma unroll
    for (int j = 0; j < 16; ++j) {
        f4 r = v[j] * scale;
        __builtin_nontemporal_store(r, &yp[j * ROW_F4]);
    }
}

extern "C" void kernel_launch(void* const* d_in, const int* in_sizes, int n_in,
                              void* d_out, int out_size, void* d_ws, size_t ws_size,
                              hipStream_t stream) {
    const float* x = (const float*)d_in[0];
    // d_in[1] (had_K) is the Sylvester Hadamard matrix by construction; FWHT replaces it.
    float* y = (float*)d_out;

    const int ntokens = in_sizes[0] / (HEADS * ROW_F4 * 4);  // 16384
    const int blocks = (ntokens + TOK_PER_BLOCK - 1) / TOK_PER_BLOCK;

    hadamard_heads_kernel<<<blocks, BLOCK, 0, stream>>>(
        (const f4*)x, (f4*)y, ntokens);
}